// Round 19
// baseline (100.478 us; speedup 1.0000x reference)
//
#include <hip/hip_runtime.h>

typedef __bf16 bf16x8 __attribute__((ext_vector_type(8)));
typedef float f32x4 __attribute__((ext_vector_type(4)));
typedef float f32x16 __attribute__((ext_vector_type(16)));

#define MFMA16(a,b,c) __builtin_amdgcn_mfma_f32_16x16x32_bf16(a,b,c,0,0,0)
#define MFMA32(a,b,c) __builtin_amdgcn_mfma_f32_32x32x16_bf16(a,b,c,0,0,0)

static __device__ __forceinline__ unsigned short f2bf(float f){
  union{float f;unsigned u;}v; v.f=f;
  unsigned u=v.u;
  u += 0x7fffu + ((u>>16)&1u);
  return (unsigned short)(u>>16);
}
static __device__ __forceinline__ float bf2f(unsigned short h){
  union{unsigned u;float f;}v; v.u=((unsigned)h)<<16; return v.f;
}
static __device__ __forceinline__ unsigned cvtpk(float lo, float hi){
  unsigned r;
  asm("v_cvt_pk_bf16_f32 %0, %1, %2" : "=v"(r) : "v"(lo), "v"(hi));
  return r;
}
static __device__ __forceinline__ void gload16(const void* g, void* l){
  __builtin_amdgcn_global_load_lds(
    (const __attribute__((address_space(1))) unsigned int*)(uintptr_t)g,
    (__attribute__((address_space(3))) unsigned int*)(uintptr_t)l,
    16, 0, 0);
}

#define SCALE_QK 0.08838834764831845f
#define LOG2E    1.44269504088896340f
// Fixed softmax shift (log2 domain). Softmax is shift-invariant; logits
// (log2) are ~N(0,1.5) with max ~5 over 4096 keys, so M0=16 keeps
// P = 2^(s-16) in [2^-40, 2^-11]: no overflow/underflow, precision exact.
#define M0_L2    16.0f

#define NSPLIT   6   /* splits per batch: grid = 4*6*32 = 768 = 3 blocks/CU */

// 16B-granule XOR swizzle for 256B-stride K tiles (short index)
#define SWZ128(r,c) (((r)<<7) + ((c) ^ (((r)&7)<<3)))

// 32x32 mappings (HW-validated via r6/r9..r18 passes):
//   C/D: col=lane&31, row=(reg&3)+8*(reg>>2)+4*(lane>>5)
//   A/B c-map (consistent pair): c = 8*(lane>>5) + j
// PV zero-exchange: sc reg r holds k=(r&3)+8*(r>>2)+4hi; V stored at
//   pos(k) = 16*(k>>4) + (k&3) + 4*((k>>3)&1) + 8*((k>>2)&1)
// -> A-frag = cvtpk(sc) in order; B-frag contiguous in V^T row-pair rows.

// ---------------------------------------------------------------------------
// Kernel 1: q/k/v projections (bf16) + combined per-key bias
//   biasc = (value@vs_w + vs_b + att_bias)*LOG2E - M0   (shift pre-folded)
// ---------------------------------------------------------------------------
__global__ __launch_bounds__(256) void k_proj(
    const float* __restrict__ query, const float* __restrict__ key,
    const float* __restrict__ value, const float* __restrict__ att_bias,
    const float* __restrict__ q_w, const float* __restrict__ q_b,
    const float* __restrict__ k_w, const float* __restrict__ v_w,
    const float* __restrict__ v_b, const float* __restrict__ vs_w,
    const float* __restrict__ vs_b,
    unsigned short* __restrict__ qp, unsigned short* __restrict__ kp,
    unsigned short* __restrict__ vpt, float* __restrict__ biasc)
{
  const int t = blockIdx.y;
  const float* X = (t==0) ? query : ((t==1) ? key : value);
  const float* W = (t==0) ? q_w  : ((t==1) ? k_w : v_w);
  const int tid = threadIdx.x;
  const int row0 = blockIdx.x * 64;

  __shared__ __align__(16) unsigned short Wt[128][136];
  __shared__ __align__(16) unsigned short Xs[64][136];
  __shared__ float vsw_s[128];

  #pragma unroll 4
  for (int i=0;i<16;i++){
    int idx = tid*64 + i*4;
    float4 v4 = *(const float4*)(W + idx);
    Wt[(idx+0)&127][(idx+0)>>7] = f2bf(v4.x);
    Wt[(idx+1)&127][(idx+1)>>7] = f2bf(v4.y);
    Wt[(idx+2)&127][(idx+2)>>7] = f2bf(v4.z);
    Wt[(idx+3)&127][(idx+3)>>7] = f2bf(v4.w);
  }
  {
    const float* Xb = X + (size_t)row0*128;
    #pragma unroll
    for (int i=0;i<8;i++){
      int f4 = i*256 + tid;
      int row = f4>>5, c4 = f4&31;
      float4 v = *(const float4*)(Xb + row*128 + c4*4);
      ushort4 h;
      h.x = f2bf(v.x); h.y = f2bf(v.y); h.z = f2bf(v.z); h.w = f2bf(v.w);
      *(ushort4*)&Xs[row][c4*4] = h;
    }
  }
  if (t==2 && tid<128) vsw_s[tid] = vs_w[tid];
  __syncthreads();

  const int w = tid>>6, lane = tid&63, lr = lane&15, lg = lane>>4;
  f32x4 acc[8];
  #pragma unroll
  for (int nt=0;nt<8;nt++) acc[nt] = (f32x4){0.f,0.f,0.f,0.f};
  #pragma unroll
  for (int kk=0;kk<4;kk++){
    bf16x8 a = *(const bf16x8*)&Xs[w*16+lr][kk*32+lg*8];
    #pragma unroll
    for (int nt=0;nt<8;nt++){
      bf16x8 bb = *(const bf16x8*)&Wt[nt*16+lr][kk*32+lg*8];
      acc[nt] = MFMA16(a,bb,acc[nt]);
    }
  }

  if (t < 2){
    const float* bias = (t==0) ? q_b : (const float*)nullptr;
    const float sc = (t==0) ? (SCALE_QK*LOG2E) : 1.f;
    unsigned short* dstm = (t==0) ? qp : kp;
    #pragma unroll
    for (int nt=0;nt<8;nt++){
      int col = nt*16+lr;
      float bv = bias ? bias[col] : 0.f;
      #pragma unroll
      for (int r=0;r<4;r++){
        int row = row0 + w*16 + lg*4 + r;
        dstm[(size_t)row*128+col] = f2bf((acc[nt][r] + bv) * sc);
      }
    }
  } else {
    {
      int rl = tid>>2, part = tid&3;
      float s = 0.f;
      #pragma unroll
      for (int j=0;j<32;j++){
        int d = part*32+j;
        s += bf2f(Xs[rl][d]) * vsw_s[d];
      }
      s += __shfl_xor(s,1);
      s += __shfl_xor(s,2);
      if ((tid&3)==0){
        int rg = row0 + rl;
        biasc[rg] = (s + vs_b[0] + att_bias[rg]) * LOG2E - M0_L2;
      }
    }
    __syncthreads();   // all Wt MFMA reads done -> reuse as Vls
    unsigned short* Vls = (unsigned short*)Wt;   // [128 d][72]
    #pragma unroll
    for (int nt=0;nt<8;nt++){
      int col = nt*16+lr;
      float bv = v_b[col];
      #pragma unroll
      for (int r=0;r<4;r++){
        int rl_ = w*16 + lg*4 + r;
        int k5 = rl_ & 31;
        int pos = 16*(k5>>4) + (k5&3) + 4*((k5>>3)&1) + 8*((k5>>2)&1);
        int np = (rl_ & 32) | pos;
        Vls[col*72 + np] = f2bf(acc[nt][r] + bv);
      }
    }
    __syncthreads();
    int d = tid>>1, half = tid&1;
    int bi = row0>>12, n0 = row0&4095;
    unsigned short* dst = vpt + ((size_t)(bi*128+d))*4096 + n0 + half*32;
    const unsigned short* src = Vls + d*72 + half*32;
    #pragma unroll
    for (int i=0;i<4;i++)
      *(uint4*)(dst + i*8) = *(const uint4*)(src + i*8);
  }
}

// ---------------------------------------------------------------------------
// Kernel 2: flash attention, 32x32x16 core, fixed-shift softmax, zero-tail
//   grid 768, triple-buffered LDS, cross-tile pipeline (r18 base).
//   NEW vs r18: exp2+rowsum(t) INTERLEAVED with QK(t+1)'s MFMAs (2 exp2 per
//   MFMA; independent chains feed VALU and matrix pipes simultaneously).
//   In r18 this ~200cy VALU-only segment sat BEFORE the asm barrier fence,
//   where no compiler scheduling could overlap it with MFMA.
//   Loop: barrier; STAGE(t+2); [QK(t+1) || exp2(t)]; pack(t); PV(t).
//   Race ledger identical to r17/r18 (only VALU work moved across fence).
// ---------------------------------------------------------------------------
__global__ __launch_bounds__(256,3) void k_flash(
    const unsigned short* __restrict__ qp, const unsigned short* __restrict__ kp,
    const unsigned short* __restrict__ vpt, const float* __restrict__ biasc,
    unsigned short* __restrict__ opart, float* __restrict__ ml)
{
  // XCD-aware decode (bijective over 768; xcd = blk&7 owns 3 (b,split) groups)
  const int f = blockIdx.x;
  const int xcd = f & 7, slot = f >> 3;          // slot 0..95
  const int group = xcd*3 + (slot>>5);           // 0..23
  const int b = group/NSPLIT, split = group%NSPLIT;
  const int q0 = (slot & 31) * 128;
  const int ts = 21*split + (split<2 ? split : 2);   // start key-tile
  const int nt = (split<2) ? 22 : 21;                // key-tiles this split

  const int tid = threadIdx.x;            // 0..255
  const int w = tid>>6, lane = tid&63;
  const int l31 = lane&31, hi = lane>>5;

  __shared__ __align__(16) unsigned short Ks[3][32*128];  // 24KB [key][d] swz
  __shared__ __align__(16) char Vp[3][8192];              // 24KB V^T row-pair swz
  __shared__ __align__(16) float Bs[768];                 // 3KB bias (split panel)

  const unsigned short* kbase = kp  + (size_t)(b*4096 + ts*32)*128;
  const char* vbase = (const char*)(vpt + (size_t)b*128*4096 + ts*32);
  const float* bbase = biasc + b*4096 + ts*32;

  // prologue: bias panel -> LDS (waves 0..2; oldest vmcnt entries)
  if (w < 3) gload16(bbase + w*256 + lane*4, (char*)Bs + w*1024);

  bf16x8 qf[8];
  {
    const unsigned short* qrow = qp + ((size_t)(b*4096 + q0 + w*32 + l31))*128;
    #pragma unroll
    for (int kk=0;kk<8;kk++) qf[kk] = *(const bf16x8*)(qrow + kk*16 + hi*8);
  }

  // stage 32-key tile; k0_ is in KEYS (tile*32). 4 gload16 per wave.
  #define STAGE(bf_, k0_) do{                                                 \
    const char* kb_ = (const char*)kbase + (size_t)(k0_)*256;                 \
    const char* vb_ = vbase + (size_t)(k0_)*2;                                \
    _Pragma("unroll")                                                         \
    for (int i=0;i<2;i++){                                                    \
      int s_ = w*2+i;                                                         \
      int kr = s_*4 + (lane>>4);                                              \
      gload16(kb_ + kr*256 + (((lane&15)*16) ^ ((kr&7)*16)),                  \
              (char*)Ks[bf_] + s_*1024);                                      \
      int u_ = (lane&7) ^ ((lane>>3)&7);                                      \
      int vd = s_*16 + ((lane>>3)<<1) + (u_>>2);                              \
      gload16(vb_ + (size_t)vd*8192 + ((u_&3)<<4),                            \
              (char*)Vp[bf_] + s_*1024);                                      \
    }                                                                         \
  }while(0)

  // bias C-init loader for tile tt (k-mapped per 32x32 C layout)
  #define BIAS_INIT(dst_, tt_) do{                                            \
    const float* Bt_ = &Bs[(tt_)*32];                                         \
    float4 c0_ = *(const float4*)&Bt_[hi*4];                                  \
    float4 c1_ = *(const float4*)&Bt_[8 + hi*4];                              \
    float4 c2_ = *(const float4*)&Bt_[16 + hi*4];                             \
    float4 c3_ = *(const float4*)&Bt_[24 + hi*4];                             \
    dst_[0]=c0_.x;  dst_[1]=c0_.y;  dst_[2]=c0_.z;  dst_[3]=c0_.w;            \
    dst_[4]=c1_.x;  dst_[5]=c1_.y;  dst_[6]=c1_.z;  dst_[7]=c1_.w;            \
    dst_[8]=c2_.x;  dst_[9]=c2_.y;  dst_[10]=c2_.z; dst_[11]=c2_.w;           \
    dst_[12]=c3_.x; dst_[13]=c3_.y; dst_[14]=c3_.z; dst_[15]=c3_.w;           \
  }while(0)

  float l_run = 0.f;
  f32x16 acc[4];
  #pragma unroll
  for (int dt=0;dt<4;dt++) acc[dt] = (f32x16){};

  // prologue: tiles 0 and 1 in flight
  STAGE(0, 0);
  STAGE(1, 32);

  // V^T read constants: row-pair rp = dt*16 + (l31>>1)
  const int vA = (l31>>1)*128;
  const int vX = ((l31>>1)&7)<<4;
  const int vH = (l31&1)*64 + hi*16;

  // drain bias + tile0 (keep tile1's 4 loads in flight), then QK(0)
  asm volatile("s_waitcnt vmcnt(4)" ::: "memory");
  __builtin_amdgcn_s_barrier();
  __builtin_amdgcn_sched_barrier(0);

  f32x16 sc_cur;
  BIAS_INIT(sc_cur, 0);
  #pragma unroll
  for (int kk=0;kk<8;kk++){
    bf16x8 a = *(const bf16x8*)&Ks[0][SWZ128(l31, kk*16 + hi*8)];
    sc_cur = MFMA32(a, qf[kk], sc_cur);
  }

  int cur = 0;   // buffer holding tile t
  for (int t=0;t<nt-1;t++){
    // ---- tile t+1 resident; all waves done reading tile t-1
    asm volatile("s_waitcnt vmcnt(0)" ::: "memory");
    __builtin_amdgcn_s_barrier();
    __builtin_amdgcn_sched_barrier(0);

    if (t+2 < nt){
      int b2 = cur+2; if (b2>=3) b2-=3;
      STAGE(b2, (t+2)*32);
    }

    int nxt = cur+1; if (nxt>=3) nxt-=3;
    const unsigned short* Kn = Ks[nxt];
    const char* Vc = Vp[cur];

    f32x16 sc_next;
    BIAS_INIT(sc_next, t+1);

    // ---- interleaved: QK(t+1) MFMAs || exp2+rowsum(t) on the VALU pipe
    float rs = 0.f;
    __builtin_amdgcn_s_setprio(1);
    #pragma unroll
    for (int kk=0;kk<8;kk++){
      bf16x8 a = *(const bf16x8*)&Kn[SWZ128(l31, kk*16 + hi*8)];
      sc_next = MFMA32(a, qf[kk], sc_next);
      sc_cur[2*kk]   = __builtin_exp2f(sc_cur[2*kk]);   rs += sc_cur[2*kk];
      sc_cur[2*kk+1] = __builtin_exp2f(sc_cur[2*kk+1]); rs += sc_cur[2*kk+1];
    }
    __builtin_amdgcn_s_setprio(0);
    rs += __shfl_xor(rs, 32);
    l_run += rs;

    // ---- pack P(t) to bf16 A-frags
    union { unsigned u[4]; bf16x8 v; } pu0, pu1;
    pu0.u[0] = cvtpk(sc_cur[0],  sc_cur[1]);
    pu0.u[1] = cvtpk(sc_cur[2],  sc_cur[3]);
    pu0.u[2] = cvtpk(sc_cur[4],  sc_cur[5]);
    pu0.u[3] = cvtpk(sc_cur[6],  sc_cur[7]);
    pu1.u[0] = cvtpk(sc_cur[8],  sc_cur[9]);
    pu1.u[1] = cvtpk(sc_cur[10], sc_cur[11]);
    pu1.u[2] = cvtpk(sc_cur[12], sc_cur[13]);
    pu1.u[3] = cvtpk(sc_cur[14], sc_cur[15]);

    // ---- PV(t)
    __builtin_amdgcn_s_setprio(1);
    #pragma unroll
    for (int kk=0;kk<8;kk++){
      const int dt = kk&3, hf = kk>>2;
      bf16x8 v = *(const bf16x8*)(Vc + dt*2048 + vA + ((vH + hf*32) ^ vX));
      acc[dt] = MFMA32(hf ? pu1.v : pu0.v, v, acc[dt]);
    }
    __builtin_amdgcn_s_setprio(0);

    sc_cur = sc_next;
    cur = nxt;
  }

  // ---- tail: tile nt-1 (V resident since the last drain+barrier)
  {
    float rs = 0.f;
    #pragma unroll
    for (int i=0;i<16;i++){
      sc_cur[i] = __builtin_exp2f(sc_cur[i]); rs += sc_cur[i];
    }
    rs += __shfl_xor(rs, 32);
    l_run += rs;
    union { unsigned u[4]; bf16x8 v; } pu0, pu1;
    pu0.u[0] = cvtpk(sc_cur[0],  sc_cur[1]);
    pu0.u[1] = cvtpk(sc_cur[2],  sc_cur[3]);
    pu0.u[2] = cvtpk(sc_cur[4],  sc_cur[5]);
    pu0.u[3] = cvtpk(sc_cur[6],  sc_cur[7]);
    pu1.u[0] = cvtpk(sc_cur[8],  sc_cur[9]);
    pu1.u[1] = cvtpk(sc_cur[10], sc_cur[11]);
    pu1.u[2] = cvtpk(sc_cur[12], sc_cur[13]);
    pu1.u[3] = cvtpk(sc_cur[14], sc_cur[15]);
    const char* Vc = Vp[cur];
    __builtin_amdgcn_s_setprio(1);
    #pragma unroll
    for (int kk=0;kk<8;kk++){
      const int dt = kk&3, hf = kk>>2;
      bf16x8 v = *(const bf16x8*)(Vc + dt*2048 + vA + ((vH + hf*32) ^ vX));
      acc[dt] = MFMA32(hf ? pu1.v : pu0.v, v, acc[dt]);
    }
    __builtin_amdgcn_s_setprio(0);
  }
  #undef STAGE
  #undef BIAS_INIT

  // ---- epilogue: lane holds O[q=(r&3)+8(r>>2)+4hi][d=dt*32+l31]
  const size_t rowbase = (size_t)split*16384 + (size_t)b*4096 + q0;
  #pragma unroll
  for (int r=0;r<16;r++){
    int qn = (r&3) + 8*(r>>2) + 4*hi;
    float inv = 1.f/__shfl(l_run, qn);
    size_t row = rowbase + w*32 + qn;
    opart[row*128 +      l31] = f2bf(acc[0][r]*inv);
    opart[row*128 + 32 + l31] = f2bf(acc[1][r]*inv);
    opart[row*128 + 64 + l31] = f2bf(acc[2][r]*inv);
    opart[row*128 + 96 + l31] = f2bf(acc[3][r]*inv);
  }
  if (hi==0){
    size_t rg = rowbase + w*32 + l31;
    ml[rg*2]   = 0.f;      // all splits share the same fixed shift
    ml[rg*2+1] = l_run;
  }
}

// ---------------------------------------------------------------------------
// Kernel 3: merge 6 KV-split partials + out-projection. 512 blocks x 32 rows.
// ---------------------------------------------------------------------------
__global__ __launch_bounds__(256) void k_outproj(
    const unsigned short* __restrict__ opart, const float* __restrict__ ml,
    const float* __restrict__ p_w, const float* __restrict__ p_b,
    float* __restrict__ out)
{
  const int tid = threadIdx.x;
  const int row0 = blockIdx.x*32;
  __shared__ __align__(16) unsigned short Wt[128][136];
  __shared__ __align__(16) unsigned short Xs[32][136];
  __shared__ float wmg[NSPLIT][32];

  #pragma unroll 4
  for (int i=0;i<16;i++){
    int idx = tid*64 + i*4;
    float4 v4 = *(const float4*)(p_w + idx);
    Wt[(idx+0)&127][(idx+0)>>7] = f2bf(v4.x);
    Wt[(idx+1)&127][(idx+1)>>7] = f2bf(v4.y);
    Wt[(idx+2)&127][(idx+2)>>7] = f2bf(v4.z);
    Wt[(idx+3)&127][(idx+3)>>7] = f2bf(v4.w);
  }
  if (tid < 32){
    int row = row0 + tid;
    float l[NSPLIT], wsum = 0.f;
    #pragma unroll
    for (int i=0;i<NSPLIT;i++){
      l[i] = ml[((size_t)i*16384 + row)*2 + 1];   // m are all 0 (fixed shift)
      wsum += l[i];
    }
    float inv = 1.f/wsum;
    #pragma unroll
    for (int i=0;i<NSPLIT;i++) wmg[i][tid] = l[i]*inv;
  }
  __syncthreads();
  #pragma unroll
  for (int i=0;i<2;i++){
    int e = (i*256 + tid)*8;
    int row = e>>7, col = e&127;
    float a8[8];
    #pragma unroll
    for (int j=0;j<8;j++) a8[j] = 0.f;
    #pragma unroll
    for (int s=0;s<NSPLIT;s++){
      uint4 v = *(const uint4*)(opart + ((size_t)s*16384 + row0 + row)*128 + col);
      float wv = wmg[s][row];
      const unsigned short* hp = (const unsigned short*)&v;
      #pragma unroll
      for (int j=0;j<8;j++) a8[j] += wv * bf2f(hp[j]);
    }
    unsigned short h8[8];
    #pragma unroll
    for (int j=0;j<8;j++) h8[j] = f2bf(a8[j]);
    *(uint4*)&Xs[row][col] = *(const uint4*)h8;
  }
  __syncthreads();

  const int w=tid>>6, lane=tid&63, lr=lane&15, lg=lane>>4;
  const int r0 = (w&1)*16, c0 = (w>>1)*64;
  f32x4 acc[4];
  #pragma unroll
  for (int nt=0;nt<4;nt++) acc[nt] = (f32x4){0.f,0.f,0.f,0.f};
  #pragma unroll
  for (int kk=0;kk<4;kk++){
    bf16x8 a = *(const bf16x8*)&Xs[r0+lr][kk*32+lg*8];
    #pragma unroll
    for (int nt=0;nt<4;nt++){
      bf16x8 bb = *(const bf16x8*)&Wt[c0+nt*16+lr][kk*32+lg*8];
      acc[nt] = MFMA16(a,bb,acc[nt]);
    }
  }
  __syncthreads();
  float* Os = (float*)Wt;      // [32][132]
  #pragma unroll
  for (int nt=0;nt<4;nt++){
    int col = c0 + nt*16 + lr;
    float pb = p_b[col];
    #pragma unroll
    for (int r=0;r<4;r++){
      int row = r0 + lg*4 + r;
      Os[row*132 + col] = acc[nt][r] + pb;
    }
  }
  __syncthreads();
  {
    int row = tid>>3, seg = tid&7;
    const float* src = Os + row*132 + seg*16;
    float* dst = out + (size_t)(row0+row)*128 + seg*16;
    #pragma unroll
    for (int i=0;i<4;i++)
      *(float4*)(dst + i*4) = *(const float4*)(src + i*4);
  }
}

extern "C" void kernel_launch(void* const* d_in, const int* in_sizes, int n_in,
                              void* d_out, int out_size, void* d_ws, size_t ws_size,
                              hipStream_t stream) {
  (void)in_sizes; (void)n_in; (void)out_size; (void)ws_size;
  const float* query    = (const float*)d_in[0];
  const float* key      = (const float*)d_in[1];
  const float* value    = (const float*)d_in[2];
  const float* att_bias = (const float*)d_in[3];
  const float* q_w = (const float*)d_in[4];
  const float* q_b = (const float*)d_in[5];
  const float* k_w = (const float*)d_in[6];
  const float* v_w = (const float*)d_in[7];
  const float* v_b = (const float*)d_in[8];
  const float* vs_w = (const float*)d_in[9];
  const float* vs_b = (const float*)d_in[10];
  const float* p_w = (const float*)d_in[11];
  const float* p_b = (const float*)d_in[12];

  char* ws = (char*)d_ws;
  unsigned short* qp    = (unsigned short*)(ws);             // 4 MB
  unsigned short* kp    = (unsigned short*)(ws + 4194304);   // 4 MB
  unsigned short* vpt   = (unsigned short*)(ws + 8388608);   // 4 MB  [b][d][n-perm]
  float*          biasc = (float*)(ws + 12582912);           // 64 KB
  unsigned short* opart = (unsigned short*)(ws + 12648448);  // 24 MB [6][16384][128]
  float*          ml    = (float*)(ws + 46202880);           // 768 KB

  hipLaunchKernelGGL(k_proj, dim3(256,3), dim3(256), 0, stream,
    query,key,value,att_bias,q_w,q_b,k_w,v_w,v_b,vs_w,vs_b,qp,kp,vpt,biasc);
  hipLaunchKernelGGL(k_flash, dim3(768), dim3(256), 0, stream,
    qp,kp,vpt,biasc,opart,ml);
  hipLaunchKernelGGL(k_outproj, dim3(512), dim3(256), 0, stream,
    opart,ml,p_w,p_b,(float*)d_out);
}

// Round 20
// 74.575 us; speedup vs baseline: 1.3473x; 1.3473x over previous
//
#include <hip/hip_runtime.h>

typedef __bf16 bf16x8 __attribute__((ext_vector_type(8)));
typedef float f32x4 __attribute__((ext_vector_type(4)));
typedef float f32x16 __attribute__((ext_vector_type(16)));

#define MFMA16(a,b,c) __builtin_amdgcn_mfma_f32_16x16x32_bf16(a,b,c,0,0,0)
#define MFMA32(a,b,c) __builtin_amdgcn_mfma_f32_32x32x16_bf16(a,b,c,0,0,0)

static __device__ __forceinline__ unsigned short f2bf(float f){
  union{float f;unsigned u;}v; v.f=f;
  unsigned u=v.u;
  u += 0x7fffu + ((u>>16)&1u);
  return (unsigned short)(u>>16);
}
static __device__ __forceinline__ float bf2f(unsigned short h){
  union{unsigned u;float f;}v; v.u=((unsigned)h)<<16; return v.f;
}
static __device__ __forceinline__ unsigned cvtpk(float lo, float hi){
  unsigned r;
  asm("v_cvt_pk_bf16_f32 %0, %1, %2" : "=v"(r) : "v"(lo), "v"(hi));
  return r;
}
static __device__ __forceinline__ void gload16(const void* g, void* l){
  __builtin_amdgcn_global_load_lds(
    (const __attribute__((address_space(1))) unsigned int*)(uintptr_t)g,
    (__attribute__((address_space(3))) unsigned int*)(uintptr_t)l,
    16, 0, 0);
}

#define SCALE_QK 0.08838834764831845f
#define LOG2E    1.44269504088896340f
// Fixed softmax shift (log2 domain). Softmax is shift-invariant; logits
// (log2) are ~N(0,1.5) with max ~5 over 4096 keys, so M0=16 keeps
// P = 2^(s-16) in [2^-40, 2^-11]: no overflow/underflow, precision exact.
#define M0_L2    16.0f

#define NSPLIT   6   /* splits per batch: grid = 4*6*32 = 768 = 3 blocks/CU */

// 16B-granule XOR swizzle for 256B-stride K tiles (short index)
#define SWZ128(r,c) (((r)<<7) + ((c) ^ (((r)&7)<<3)))

// 32x32 mappings (HW-validated via r6/r9..r18 passes):
//   C/D: col=lane&31, row=(reg&3)+8*(reg>>2)+4*(lane>>5)
//   A/B c-map (consistent pair): c = 8*(lane>>5) + j
// PV zero-exchange: sc reg r holds k=(r&3)+8*(r>>2)+4hi; V stored at
//   pos(k) = 16*(k>>4) + (k&3) + 4*((k>>3)&1) + 8*((k>>2)&1)
// -> A-frag = cvtpk(sc) in order; B-frag contiguous in V^T row-pair rows.

// ---------------------------------------------------------------------------
// Kernel 1: q/k/v projections (bf16) + combined per-key bias
//   biasc = (value@vs_w + vs_b + att_bias)*LOG2E - M0   (shift pre-folded)
// ---------------------------------------------------------------------------
__global__ __launch_bounds__(256) void k_proj(
    const float* __restrict__ query, const float* __restrict__ key,
    const float* __restrict__ value, const float* __restrict__ att_bias,
    const float* __restrict__ q_w, const float* __restrict__ q_b,
    const float* __restrict__ k_w, const float* __restrict__ v_w,
    const float* __restrict__ v_b, const float* __restrict__ vs_w,
    const float* __restrict__ vs_b,
    unsigned short* __restrict__ qp, unsigned short* __restrict__ kp,
    unsigned short* __restrict__ vpt, float* __restrict__ biasc)
{
  const int t = blockIdx.y;
  const float* X = (t==0) ? query : ((t==1) ? key : value);
  const float* W = (t==0) ? q_w  : ((t==1) ? k_w : v_w);
  const int tid = threadIdx.x;
  const int row0 = blockIdx.x * 64;

  __shared__ __align__(16) unsigned short Wt[128][136];
  __shared__ __align__(16) unsigned short Xs[64][136];
  __shared__ float vsw_s[128];

  #pragma unroll 4
  for (int i=0;i<16;i++){
    int idx = tid*64 + i*4;
    float4 v4 = *(const float4*)(W + idx);
    Wt[(idx+0)&127][(idx+0)>>7] = f2bf(v4.x);
    Wt[(idx+1)&127][(idx+1)>>7] = f2bf(v4.y);
    Wt[(idx+2)&127][(idx+2)>>7] = f2bf(v4.z);
    Wt[(idx+3)&127][(idx+3)>>7] = f2bf(v4.w);
  }
  {
    const float* Xb = X + (size_t)row0*128;
    #pragma unroll
    for (int i=0;i<8;i++){
      int f4 = i*256 + tid;
      int row = f4>>5, c4 = f4&31;
      float4 v = *(const float4*)(Xb + row*128 + c4*4);
      ushort4 h;
      h.x = f2bf(v.x); h.y = f2bf(v.y); h.z = f2bf(v.z); h.w = f2bf(v.w);
      *(ushort4*)&Xs[row][c4*4] = h;
    }
  }
  if (t==2 && tid<128) vsw_s[tid] = vs_w[tid];
  __syncthreads();

  const int w = tid>>6, lane = tid&63, lr = lane&15, lg = lane>>4;
  f32x4 acc[8];
  #pragma unroll
  for (int nt=0;nt<8;nt++) acc[nt] = (f32x4){0.f,0.f,0.f,0.f};
  #pragma unroll
  for (int kk=0;kk<4;kk++){
    bf16x8 a = *(const bf16x8*)&Xs[w*16+lr][kk*32+lg*8];
    #pragma unroll
    for (int nt=0;nt<8;nt++){
      bf16x8 bb = *(const bf16x8*)&Wt[nt*16+lr][kk*32+lg*8];
      acc[nt] = MFMA16(a,bb,acc[nt]);
    }
  }

  if (t < 2){
    const float* bias = (t==0) ? q_b : (const float*)nullptr;
    const float sc = (t==0) ? (SCALE_QK*LOG2E) : 1.f;
    unsigned short* dstm = (t==0) ? qp : kp;
    #pragma unroll
    for (int nt=0;nt<8;nt++){
      int col = nt*16+lr;
      float bv = bias ? bias[col] : 0.f;
      #pragma unroll
      for (int r=0;r<4;r++){
        int row = row0 + w*16 + lg*4 + r;
        dstm[(size_t)row*128+col] = f2bf((acc[nt][r] + bv) * sc);
      }
    }
  } else {
    {
      int rl = tid>>2, part = tid&3;
      float s = 0.f;
      #pragma unroll
      for (int j=0;j<32;j++){
        int d = part*32+j;
        s += bf2f(Xs[rl][d]) * vsw_s[d];
      }
      s += __shfl_xor(s,1);
      s += __shfl_xor(s,2);
      if ((tid&3)==0){
        int rg = row0 + rl;
        biasc[rg] = (s + vs_b[0] + att_bias[rg]) * LOG2E - M0_L2;
      }
    }
    __syncthreads();   // all Wt MFMA reads done -> reuse as Vls
    unsigned short* Vls = (unsigned short*)Wt;   // [128 d][72]
    #pragma unroll
    for (int nt=0;nt<8;nt++){
      int col = nt*16+lr;
      float bv = v_b[col];
      #pragma unroll
      for (int r=0;r<4;r++){
        int rl_ = w*16 + lg*4 + r;
        int k5 = rl_ & 31;
        int pos = 16*(k5>>4) + (k5&3) + 4*((k5>>3)&1) + 8*((k5>>2)&1);
        int np = (rl_ & 32) | pos;
        Vls[col*72 + np] = f2bf(acc[nt][r] + bv);
      }
    }
    __syncthreads();
    int d = tid>>1, half = tid&1;
    int bi = row0>>12, n0 = row0&4095;
    unsigned short* dst = vpt + ((size_t)(bi*128+d))*4096 + n0 + half*32;
    const unsigned short* src = Vls + d*72 + half*32;
    #pragma unroll
    for (int i=0;i<4;i++)
      *(uint4*)(dst + i*8) = *(const uint4*)(src + i*8);
  }
}

// ---------------------------------------------------------------------------
// Kernel 2: flash attention, 32x32x16 core, fixed-shift softmax, zero-tail
//   grid 768, triple-buffered LDS, cross-tile software pipeline (r18, the
//   best verified configuration): QK(t+1) interleaved 1:1 with PV(t) (two
//   independent MFMA chains), exp2/pack(t) before the barrier.
//   Loop: exp2/pack(sc_cur); vmcnt(0)+barrier; STAGE(t+2); [QK(t+1)||PV(t)].
//   Race ledger (verified r17/r18): reads of buf b retire before the
//   barrier preceding its overwrite; each wave drains its own stage loads
//   at vmcnt(0); prologue vmcnt(4) drains bias+tile0, keeps tile1 in flight.
// ---------------------------------------------------------------------------
__global__ __launch_bounds__(256,3) void k_flash(
    const unsigned short* __restrict__ qp, const unsigned short* __restrict__ kp,
    const unsigned short* __restrict__ vpt, const float* __restrict__ biasc,
    unsigned short* __restrict__ opart, float* __restrict__ ml)
{
  // XCD-aware decode (bijective over 768; xcd = blk&7 owns 3 (b,split) groups)
  const int f = blockIdx.x;
  const int xcd = f & 7, slot = f >> 3;          // slot 0..95
  const int group = xcd*3 + (slot>>5);           // 0..23
  const int b = group/NSPLIT, split = group%NSPLIT;
  const int q0 = (slot & 31) * 128;
  const int ts = 21*split + (split<2 ? split : 2);   // start key-tile
  const int nt = (split<2) ? 22 : 21;                // key-tiles this split

  const int tid = threadIdx.x;            // 0..255
  const int w = tid>>6, lane = tid&63;
  const int l31 = lane&31, hi = lane>>5;

  __shared__ __align__(16) unsigned short Ks[3][32*128];  // 24KB [key][d] swz
  __shared__ __align__(16) char Vp[3][8192];              // 24KB V^T row-pair swz
  __shared__ __align__(16) float Bs[768];                 // 3KB bias (split panel)

  const unsigned short* kbase = kp  + (size_t)(b*4096 + ts*32)*128;
  const char* vbase = (const char*)(vpt + (size_t)b*128*4096 + ts*32);
  const float* bbase = biasc + b*4096 + ts*32;

  // prologue: bias panel -> LDS (waves 0..2; oldest vmcnt entries)
  if (w < 3) gload16(bbase + w*256 + lane*4, (char*)Bs + w*1024);

  bf16x8 qf[8];
  {
    const unsigned short* qrow = qp + ((size_t)(b*4096 + q0 + w*32 + l31))*128;
    #pragma unroll
    for (int kk=0;kk<8;kk++) qf[kk] = *(const bf16x8*)(qrow + kk*16 + hi*8);
  }

  // stage 32-key tile; k0_ is in KEYS (tile*32). 4 gload16 per wave.
  #define STAGE(bf_, k0_) do{                                                 \
    const char* kb_ = (const char*)kbase + (size_t)(k0_)*256;                 \
    const char* vb_ = vbase + (size_t)(k0_)*2;                                \
    _Pragma("unroll")                                                         \
    for (int i=0;i<2;i++){                                                    \
      int s_ = w*2+i;                                                         \
      int kr = s_*4 + (lane>>4);                                              \
      gload16(kb_ + kr*256 + (((lane&15)*16) ^ ((kr&7)*16)),                  \
              (char*)Ks[bf_] + s_*1024);                                      \
      int u_ = (lane&7) ^ ((lane>>3)&7);                                      \
      int vd = s_*16 + ((lane>>3)<<1) + (u_>>2);                              \
      gload16(vb_ + (size_t)vd*8192 + ((u_&3)<<4),                            \
              (char*)Vp[bf_] + s_*1024);                                      \
    }                                                                         \
  }while(0)

  // bias C-init loader for tile tt (k-mapped per 32x32 C layout)
  #define BIAS_INIT(dst_, tt_) do{                                            \
    const float* Bt_ = &Bs[(tt_)*32];                                         \
    float4 c0_ = *(const float4*)&Bt_[hi*4];                                  \
    float4 c1_ = *(const float4*)&Bt_[8 + hi*4];                              \
    float4 c2_ = *(const float4*)&Bt_[16 + hi*4];                             \
    float4 c3_ = *(const float4*)&Bt_[24 + hi*4];                             \
    dst_[0]=c0_.x;  dst_[1]=c0_.y;  dst_[2]=c0_.z;  dst_[3]=c0_.w;            \
    dst_[4]=c1_.x;  dst_[5]=c1_.y;  dst_[6]=c1_.z;  dst_[7]=c1_.w;            \
    dst_[8]=c2_.x;  dst_[9]=c2_.y;  dst_[10]=c2_.z; dst_[11]=c2_.w;           \
    dst_[12]=c3_.x; dst_[13]=c3_.y; dst_[14]=c3_.z; dst_[15]=c3_.w;           \
  }while(0)

  float l_run = 0.f;
  f32x16 acc[4];
  #pragma unroll
  for (int dt=0;dt<4;dt++) acc[dt] = (f32x16){};

  // prologue: tiles 0 and 1 in flight
  STAGE(0, 0);
  STAGE(1, 32);

  // V^T read constants: row-pair rp = dt*16 + (l31>>1)
  const int vA = (l31>>1)*128;
  const int vX = ((l31>>1)&7)<<4;
  const int vH = (l31&1)*64 + hi*16;

  // drain bias + tile0 (keep tile1's 4 loads in flight), then QK(0)
  asm volatile("s_waitcnt vmcnt(4)" ::: "memory");
  __builtin_amdgcn_s_barrier();
  __builtin_amdgcn_sched_barrier(0);

  f32x16 sc_cur;
  BIAS_INIT(sc_cur, 0);
  #pragma unroll
  for (int kk=0;kk<8;kk++){
    bf16x8 a = *(const bf16x8*)&Ks[0][SWZ128(l31, kk*16 + hi*8)];
    sc_cur = MFMA32(a, qf[kk], sc_cur);
  }

  int cur = 0;   // buffer holding tile t
  for (int t=0;t<nt-1;t++){
    // ---- exp2 + row sum + pack for tile t (pre-barrier; no LDS)
    float rs = 0.f;
    #pragma unroll
    for (int i=0;i<16;i++){
      sc_cur[i] = __builtin_exp2f(sc_cur[i]); rs += sc_cur[i];
    }
    rs += __shfl_xor(rs, 32);
    l_run += rs;
    union { unsigned u[4]; bf16x8 v; } pu0, pu1;
    pu0.u[0] = cvtpk(sc_cur[0],  sc_cur[1]);
    pu0.u[1] = cvtpk(sc_cur[2],  sc_cur[3]);
    pu0.u[2] = cvtpk(sc_cur[4],  sc_cur[5]);
    pu0.u[3] = cvtpk(sc_cur[6],  sc_cur[7]);
    pu1.u[0] = cvtpk(sc_cur[8],  sc_cur[9]);
    pu1.u[1] = cvtpk(sc_cur[10], sc_cur[11]);
    pu1.u[2] = cvtpk(sc_cur[12], sc_cur[13]);
    pu1.u[3] = cvtpk(sc_cur[14], sc_cur[15]);

    // ---- tile t+1 resident; all waves done reading tile t-1
    asm volatile("s_waitcnt vmcnt(0)" ::: "memory");
    __builtin_amdgcn_s_barrier();
    __builtin_amdgcn_sched_barrier(0);

    if (t+2 < nt){
      int b2 = cur+2; if (b2>=3) b2-=3;
      STAGE(b2, (t+2)*32);
    }

    int nxt = cur+1; if (nxt>=3) nxt-=3;
    const unsigned short* Kn = Ks[nxt];
    const char* Vc = Vp[cur];

    f32x16 sc_next;
    BIAS_INIT(sc_next, t+1);

    // ---- interleaved QK(t+1) || PV(t): two independent MFMA chains
    __builtin_amdgcn_s_setprio(1);
    #pragma unroll
    for (int kk=0;kk<8;kk++){
      bf16x8 a = *(const bf16x8*)&Kn[SWZ128(l31, kk*16 + hi*8)];
      sc_next = MFMA32(a, qf[kk], sc_next);
      const int dt = kk&3, hf = kk>>2;
      bf16x8 v = *(const bf16x8*)(Vc + dt*2048 + vA + ((vH + hf*32) ^ vX));
      acc[dt] = MFMA32(hf ? pu1.v : pu0.v, v, acc[dt]);
    }
    __builtin_amdgcn_s_setprio(0);

    sc_cur = sc_next;
    cur = nxt;
  }

  // ---- tail: tile nt-1 (V resident since iter nt-2's drain+barrier)
  {
    float rs = 0.f;
    #pragma unroll
    for (int i=0;i<16;i++){
      sc_cur[i] = __builtin_exp2f(sc_cur[i]); rs += sc_cur[i];
    }
    rs += __shfl_xor(rs, 32);
    l_run += rs;
    union { unsigned u[4]; bf16x8 v; } pu0, pu1;
    pu0.u[0] = cvtpk(sc_cur[0],  sc_cur[1]);
    pu0.u[1] = cvtpk(sc_cur[2],  sc_cur[3]);
    pu0.u[2] = cvtpk(sc_cur[4],  sc_cur[5]);
    pu0.u[3] = cvtpk(sc_cur[6],  sc_cur[7]);
    pu1.u[0] = cvtpk(sc_cur[8],  sc_cur[9]);
    pu1.u[1] = cvtpk(sc_cur[10], sc_cur[11]);
    pu1.u[2] = cvtpk(sc_cur[12], sc_cur[13]);
    pu1.u[3] = cvtpk(sc_cur[14], sc_cur[15]);
    const char* Vc = Vp[cur];
    __builtin_amdgcn_s_setprio(1);
    #pragma unroll
    for (int kk=0;kk<8;kk++){
      const int dt = kk&3, hf = kk>>2;
      bf16x8 v = *(const bf16x8*)(Vc + dt*2048 + vA + ((vH + hf*32) ^ vX));
      acc[dt] = MFMA32(hf ? pu1.v : pu0.v, v, acc[dt]);
    }
    __builtin_amdgcn_s_setprio(0);
  }
  #undef STAGE
  #undef BIAS_INIT

  // ---- epilogue: lane holds O[q=(r&3)+8(r>>2)+4hi][d=dt*32+l31]
  const size_t rowbase = (size_t)split*16384 + (size_t)b*4096 + q0;
  #pragma unroll
  for (int r=0;r<16;r++){
    int qn = (r&3) + 8*(r>>2) + 4*hi;
    float inv = 1.f/__shfl(l_run, qn);
    size_t row = rowbase + w*32 + qn;
    opart[row*128 +      l31] = f2bf(acc[0][r]*inv);
    opart[row*128 + 32 + l31] = f2bf(acc[1][r]*inv);
    opart[row*128 + 64 + l31] = f2bf(acc[2][r]*inv);
    opart[row*128 + 96 + l31] = f2bf(acc[3][r]*inv);
  }
  if (hi==0){
    size_t rg = rowbase + w*32 + l31;
    ml[rg*2]   = 0.f;      // all splits share the same fixed shift
    ml[rg*2+1] = l_run;
  }
}

// ---------------------------------------------------------------------------
// Kernel 3: merge 6 KV-split partials + out-projection. 512 blocks x 32 rows.
// ---------------------------------------------------------------------------
__global__ __launch_bounds__(256) void k_outproj(
    const unsigned short* __restrict__ opart, const float* __restrict__ ml,
    const float* __restrict__ p_w, const float* __restrict__ p_b,
    float* __restrict__ out)
{
  const int tid = threadIdx.x;
  const int row0 = blockIdx.x*32;
  __shared__ __align__(16) unsigned short Wt[128][136];
  __shared__ __align__(16) unsigned short Xs[32][136];
  __shared__ float wmg[NSPLIT][32];

  #pragma unroll 4
  for (int i=0;i<16;i++){
    int idx = tid*64 + i*4;
    float4 v4 = *(const float4*)(p_w + idx);
    Wt[(idx+0)&127][(idx+0)>>7] = f2bf(v4.x);
    Wt[(idx+1)&127][(idx+1)>>7] = f2bf(v4.y);
    Wt[(idx+2)&127][(idx+2)>>7] = f2bf(v4.z);
    Wt[(idx+3)&127][(idx+3)>>7] = f2bf(v4.w);
  }
  if (tid < 32){
    int row = row0 + tid;
    float l[NSPLIT], wsum = 0.f;
    #pragma unroll
    for (int i=0;i<NSPLIT;i++){
      l[i] = ml[((size_t)i*16384 + row)*2 + 1];   // m are all 0 (fixed shift)
      wsum += l[i];
    }
    float inv = 1.f/wsum;
    #pragma unroll
    for (int i=0;i<NSPLIT;i++) wmg[i][tid] = l[i]*inv;
  }
  __syncthreads();
  #pragma unroll
  for (int i=0;i<2;i++){
    int e = (i*256 + tid)*8;
    int row = e>>7, col = e&127;
    float a8[8];
    #pragma unroll
    for (int j=0;j<8;j++) a8[j] = 0.f;
    #pragma unroll
    for (int s=0;s<NSPLIT;s++){
      uint4 v = *(const uint4*)(opart + ((size_t)s*16384 + row0 + row)*128 + col);
      float wv = wmg[s][row];
      const unsigned short* hp = (const unsigned short*)&v;
      #pragma unroll
      for (int j=0;j<8;j++) a8[j] += wv * bf2f(hp[j]);
    }
    unsigned short h8[8];
    #pragma unroll
    for (int j=0;j<8;j++) h8[j] = f2bf(a8[j]);
    *(uint4*)&Xs[row][col] = *(const uint4*)h8;
  }
  __syncthreads();

  const int w=tid>>6, lane=tid&63, lr=lane&15, lg=lane>>4;
  const int r0 = (w&1)*16, c0 = (w>>1)*64;
  f32x4 acc[4];
  #pragma unroll
  for (int nt=0;nt<4;nt++) acc[nt] = (f32x4){0.f,0.f,0.f,0.f};
  #pragma unroll
  for (int kk=0;kk<4;kk++){
    bf16x8 a = *(const bf16x8*)&Xs[r0+lr][kk*32+lg*8];
    #pragma unroll
    for (int nt=0;nt<4;nt++){
      bf16x8 bb = *(const bf16x8*)&Wt[c0+nt*16+lr][kk*32+lg*8];
      acc[nt] = MFMA16(a,bb,acc[nt]);
    }
  }
  __syncthreads();
  float* Os = (float*)Wt;      // [32][132]
  #pragma unroll
  for (int nt=0;nt<4;nt++){
    int col = c0 + nt*16 + lr;
    float pb = p_b[col];
    #pragma unroll
    for (int r=0;r<4;r++){
      int row = r0 + lg*4 + r;
      Os[row*132 + col] = acc[nt][r] + pb;
    }
  }
  __syncthreads();
  {
    int row = tid>>3, seg = tid&7;
    const float* src = Os + row*132 + seg*16;
    float* dst = out + (size_t)(row0+row)*128 + seg*16;
    #pragma unroll
    for (int i=0;i<4;i++)
      *(float4*)(dst + i*4) = *(const float4*)(src + i*4);
  }
}

extern "C" void kernel_launch(void* const* d_in, const int* in_sizes, int n_in,
                              void* d_out, int out_size, void* d_ws, size_t ws_size,
                              hipStream_t stream) {
  (void)in_sizes; (void)n_in; (void)out_size; (void)ws_size;
  const float* query    = (const float*)d_in[0];
  const float* key      = (const float*)d_in[1];
  const float* value    = (const float*)d_in[2];
  const float* att_bias = (const float*)d_in[3];
  const float* q_w = (const float*)d_in[4];
  const float* q_b = (const float*)d_in[5];
  const float* k_w = (const float*)d_in[6];
  const float* v_w = (const float*)d_in[7];
  const float* v_b = (const float*)d_in[8];
  const float* vs_w = (const float*)d_in[9];
  const float* vs_b = (const float*)d_in[10];
  const float* p_w = (const float*)d_in[11];
  const float* p_b = (const float*)d_in[12];

  char* ws = (char*)d_ws;
  unsigned short* qp    = (unsigned short*)(ws);             // 4 MB
  unsigned short* kp    = (unsigned short*)(ws + 4194304);   // 4 MB
  unsigned short* vpt   = (unsigned short*)(ws + 8388608);   // 4 MB  [b][d][n-perm]
  float*          biasc = (float*)(ws + 12582912);           // 64 KB
  unsigned short* opart = (unsigned short*)(ws + 12648448);  // 24 MB [6][16384][128]
  float*          ml    = (float*)(ws + 46202880);           // 768 KB

  hipLaunchKernelGGL(k_proj, dim3(256,3), dim3(256), 0, stream,
    query,key,value,att_bias,q_w,q_b,k_w,v_w,v_b,vs_w,vs_b,qp,kp,vpt,biasc);
  hipLaunchKernelGGL(k_flash, dim3(768), dim3(256), 0, stream,
    qp,kp,vpt,biasc,opart,ml);
  hipLaunchKernelGGL(k_outproj, dim3(512), dim3(256), 0, stream,
    opart,ml,p_w,p_b,(float*)d_out);
}